// Round 1
// baseline (87.975 us; speedup 1.0000x reference)
//
#include <hip/hip_runtime.h>

#define HDIM 1024
#define NMAX 10
#define KPL 16          // hidden units per lane (1024 / 64)

__device__ __forceinline__ float wsum64(float v) {
    v += __shfl_xor(v, 32, 64);
    v += __shfl_xor(v, 16, 64);
    v += __shfl_xor(v,  8, 64);
    v += __shfl_xor(v,  4, 64);
    v += __shfl_xor(v,  2, 64);
    v += __shfl_xor(v,  1, 64);
    return v;   // uniform across all 64 lanes
}

__device__ __forceinline__ float elu_f(float p) {
    // jax.nn.elu: x>0 ? x : expm1(x).  exp computed unconditionally; inf on the
    // positive side is discarded by the select (no NaN path).
    return p > 0.f ? p : (__expf(p) - 1.f);
}

__device__ __forceinline__ float mlp_eval(const float (&wy)[KPL], const float (&u)[KPL],
                                          const float (&w2)[KPL], float yy, float bias) {
    float a0 = 0.f, a1 = 0.f, a2 = 0.f, a3 = 0.f;
#pragma unroll
    for (int k = 0; k < KPL; k += 4) {
        a0 = fmaf(w2[k + 0], elu_f(fmaf(wy[k + 0], yy, u[k + 0])), a0);
        a1 = fmaf(w2[k + 1], elu_f(fmaf(wy[k + 1], yy, u[k + 1])), a1);
        a2 = fmaf(w2[k + 2], elu_f(fmaf(wy[k + 2], yy, u[k + 2])), a2);
        a3 = fmaf(w2[k + 3], elu_f(fmaf(wy[k + 3], yy, u[k + 3])), a3);
    }
    return wsum64((a0 + a1) + (a2 + a3)) + bias;
}

__global__ __launch_bounds__(256) void rmodel_kernel(
    const float* __restrict__ X, const float* __restrict__ Y,
    const float* __restrict__ de_W1, const float* __restrict__ de_b1,
    const float* __restrict__ de_W2, const float* __restrict__ de_b2,
    const float* __restrict__ val_W1, const float* __restrict__ val_b1,
    const float* __restrict__ val_W2, const float* __restrict__ val_b2,
    float* __restrict__ out, int n)
{
    const int wid  = threadIdx.x >> 6;
    const int lane = threadIdx.x & 63;
    const int b    = blockIdx.x * 4 + wid;
    if (b >= n) return;

    // ---- per-wave setup: weights -> registers, hoist x-dependent part ----
    float dwy[KPL], du[KPL], dw2[KPL];
    float vwy[KPL], vu[KPL], vw2[KPL];

    const float x = X[b];
    float y = Y[b];

#pragma unroll
    for (int k = 0; k < KPL; ++k) {
        const int h = k * 64 + lane;
        float2 w1d = reinterpret_cast<const float2*>(de_W1)[h];   // de_W1[h][0..1]
        dwy[k] = w1d.y;
        du[k]  = fmaf(w1d.x, x, de_b1[h]);                        // u = w0*x + b1
        dw2[k] = de_W2[h];
        float2 w1v = reinterpret_cast<const float2*>(val_W1)[h];
        vwy[k] = w1v.y;
        vu[k]  = fmaf(w1v.x, x, val_b1[h]);
        vw2[k] = val_W2[h];
    }
    const float db2 = de_b2[0];
    const float vb2 = val_b2[0];

    float* __restrict__ yout = out;            // [NMAX+1][n]
    float* __restrict__ vout = out + (NMAX + 1) * (size_t)n;

    // ---- v0 = val([x, y0]) ----
    float v = mlp_eval(vwy, vu, vw2, y, vb2);
    if (lane == 0) { yout[b] = y; vout[b] = v; }
    float vprev = v;

    // ---- sequential steps with wave-uniform early exit ----
    int i = 0;
    for (; i < NMAX; ++i) {
        float d    = mlp_eval(dwy, du, dw2, y, db2);
        float ynew = y + d;
        float vnew = mlp_eval(vwy, vu, vw2, ynew, vb2);
        if (lane == 0) {
            yout[(size_t)(i + 1) * n + b] = ynew;
            vout[(size_t)(i + 1) * n + b] = vnew;
        }
        y = ynew;
        bool brk = (i > 0) && (vnew >= vprev);
        vprev = vnew;
        if (brk) break;
    }

    // ---- fill frozen rows (samples that broke keep last appended values) ----
    if (lane == 0) {
        for (int j = i + 1; j < NMAX; ++j) {
            yout[(size_t)(j + 1) * n + b] = y;
            vout[(size_t)(j + 1) * n + b] = vprev;
        }
    }
}

extern "C" void kernel_launch(void* const* d_in, const int* in_sizes, int n_in,
                              void* d_out, int out_size, void* d_ws, size_t ws_size,
                              hipStream_t stream) {
    const float* X      = (const float*)d_in[0];
    const float* Y      = (const float*)d_in[1];
    const float* de_W1  = (const float*)d_in[2];
    const float* de_b1  = (const float*)d_in[3];
    const float* de_W2  = (const float*)d_in[4];
    const float* de_b2  = (const float*)d_in[5];
    const float* val_W1 = (const float*)d_in[6];
    const float* val_b1 = (const float*)d_in[7];
    const float* val_W2 = (const float*)d_in[8];
    const float* val_b2 = (const float*)d_in[9];
    float* out = (float*)d_out;

    const int n = in_sizes[0];               // 16384 samples
    dim3 block(256);                          // 4 waves/block, 1 wave = 1 sample
    dim3 grid((n + 3) / 4);
    hipLaunchKernelGGL(rmodel_kernel, grid, block, 0, stream,
                       X, Y, de_W1, de_b1, de_W2, de_b2,
                       val_W1, val_b1, val_W2, val_b2, out, n);
}